// Round 11
// baseline (2100.918 us; speedup 1.0000x reference)
//
#include <hip/hip_runtime.h>

// VQ-VAE VectorQuantizer forward + EMA update, MI355X (gfx950).
// R2-R9: fp32-VALU distance GEMM plateau 810-975us (dual 437us FMA+LDS
//   walls). R11/R12: bf16 MFMA filter + exact re-rank PASSED (bit-exact on
//   HW) but k_mfma pinned at EXACTLY 1043us across two different bodies,
//   all pipes <3% busy -> per-wave stall ~50us. Shared element: regular
//   vector loads from d_out scratch. Every fast kernel (R2-R8, 796GB/s)
//   read d_out scratch ONLY via global_load_lds.
// R13: zero regular d_out reads on the hot path:
//   - A-fragments staged per-kt (4KB dbuf) via global_load_lds; B panel
//     (64KB, full K) staged once; thr staged via global_load_lds.
//   - grid 2048 (4 row-blocks per block reuse B panel).
//   - vbuf deleted: pass-0 atomicMin(fkey(min)) into u32[NTOK] in d_ws
//     (aliases idx_ws; lifetimes disjoint). k_minred = tiny ws-only pass.
//   - epilogue math / collect / rerank / outputs verbatim from passing R12.
//   Soundness unchanged: thr = m + 0.0334*sqrt(x2*w2max)+4e-4 >= m+2E_true;
//   rerank recomputes EXACT fp32 chain (d asc) + identical epilogue
//   rounding; atomicMin on (total-order key<<32|code) => bit-exact.

#define NTOK 16384
#define KC   8192
#define DD   256

#define OFF_Q    0
#define OFF_LOSS 4194304
#define OFF_IDX  4194305
#define OFF_W    4210689
#define OFF_CS   6307841
#define OFF_EMA  6316033

#define DECAY_F  0.99f
#define OMD_F    0.01f
#define EPS_F    1e-5f
#define KEPS_F   0.08192f   // K * eps
#define CAP      786432

typedef unsigned int u32;
typedef unsigned long long u64;
typedef unsigned short u16;
typedef __attribute__((ext_vector_type(8))) short short8;     // 8 bf16
typedef __attribute__((ext_vector_type(16))) float f32x16;    // MFMA acc
typedef __attribute__((address_space(3))) unsigned int lds_u;
typedef const __attribute__((address_space(1))) unsigned int glob_u;

// total-order monotone float->u32 key (handles any sign)
__device__ __forceinline__ u32 fkey(float f) {
    u32 u = __float_as_uint(f);
    return (u & 0x80000000u) ? ~u : (u | 0x80000000u);
}

// ---- numpy-pairwise row squared-norms (n=256): bit-exact vs numpy --------
__global__ __launch_bounds__(256) void k_rownorm(const float* __restrict__ a,
                                                 float* __restrict__ outn) {
    const int wave = threadIdx.x >> 6, lane = threadIdx.x & 63;
    const int row  = blockIdx.x * 16 + wave * 4 + (lane >> 4);
    const int p    = lane & 15;
    const int h    = p >> 3, j = p & 7;
    const float* base = a + row * DD + h * 128 + j;
    float v = base[0];
    float r = __fmul_rn(v, v);
    #pragma unroll
    for (int t = 1; t < 16; ++t) {
        v = base[8 * t];
        r = __fadd_rn(r, __fmul_rn(v, v));
    }
    r = __fadd_rn(r, __shfl_xor(r, 1));
    r = __fadd_rn(r, __shfl_xor(r, 2));
    r = __fadd_rn(r, __shfl_xor(r, 4));
    r = __fadd_rn(r, __shfl_xor(r, 8));
    if (p == 0) outn[row] = r;
}

// ---------------- w2max + zero candidate counter ---------------------------
__global__ __launch_bounds__(256) void k_w2max(const float* __restrict__ w2v,
                                               float* __restrict__ w2max,
                                               int* __restrict__ counter) {
    const int t = threadIdx.x;
    float m = 0.0f;
    for (int i = t; i < KC; i += 256) m = fmaxf(m, w2v[i]);
    #pragma unroll
    for (int off = 32; off; off >>= 1) m = fmaxf(m, __shfl_down(m, off, 64));
    __shared__ float ps[4];
    if ((t & 63) == 0) ps[t >> 6] = m;
    __syncthreads();
    if (t == 0) {
        *w2max = fmaxf(fmaxf(ps[0], ps[1]), fmaxf(ps[2], ps[3]));
        *counter = 0;
    }
}

// ---------------- fp32 -> bf16 fragment-ordered conversion -----------------
// frag element t = (rt*16+kt)*64 + l holds in[rt*32 + (l&31)][kt*16 +
// 8*(l>>5) .. +8] as 8 RNE bf16. Also inits best64 / thrmin when given.
__global__ __launch_bounds__(256) void k_cvt(const float* __restrict__ in,
                                             u16* __restrict__ outf, int nrt,
                                             u64* __restrict__ binit, int nbin,
                                             u32* __restrict__ tinit) {
    const int t = blockIdx.x * 256 + threadIdx.x;
    if (binit && t < nbin) binit[t] = ~0ull;
    if (tinit && t < NTOK) tinit[t] = ~0u;
    if (t >= nrt * 1024) return;
    const int l = t & 63, kt = (t >> 6) & 15, rt = t >> 10;
    const float* src = in + (size_t)(rt * 32 + (l & 31)) * DD
                          + kt * 16 + 8 * (l >> 5);
    u32 p[4];
    #pragma unroll
    for (int e = 0; e < 4; ++e) {
        u32 b0 = __float_as_uint(src[2 * e]);
        u32 b1 = __float_as_uint(src[2 * e + 1]);
        b0 = (b0 + 0x7fffu + ((b0 >> 16) & 1u)) >> 16;   // RNE
        b1 = (b1 + 0x7fffu + ((b1 >> 16) & 1u)) >> 16;
        p[e] = b0 | (b1 << 16);
    }
    *(uint4*)(outf + (size_t)t * 8) = make_uint4(p[0], p[1], p[2], p[3]);
}

// ---------------- MFMA approx-distance pass (all-DMA staging) --------------
// grid 2048: rbg = bid&31 (4 row-blocks each), cb = bid>>5 (128 codes).
// B panel (64KB, full K) staged once; per rb: A staged per-kt (4KB dbuf);
// all d_out reads via global_load_lds. Wave wv: rhalf=wv&1, chalf=wv>>1,
// 2x2 accs. COLLECT=0: per-row wave-min -> atomicMin(fkey) into thrmin(ws).
// COLLECT=1: dist<=sthr[row] -> atomic-append (row<<13|code) to list.
template<int COLLECT>
__global__ __launch_bounds__(256) void k_mfma(
        const u16* __restrict__ zb, const u16* __restrict__ wb,
        const float* __restrict__ x2v, const float* __restrict__ w2v,
        const float* __restrict__ thr, u32* __restrict__ thrmin,
        u32* __restrict__ list, int* __restrict__ counter) {
    __shared__ short8 Bs[4096];       // 64 KB: [ct_local*1024 + kt*64 + l]
    __shared__ short8 As[2][256];     // 8 KB dbuf: [buf][rt_local*64 + l]
    __shared__ float sx2[128];
    __shared__ float sthr[256];       // upper 128 = harmless overread

    const int tid = threadIdx.x;
    const int l = tid & 63, wv = tid >> 6;
    const int rbg = blockIdx.x & 31, cb = blockIdx.x >> 5;

    // stage B panel once (16 DMA loads/thread; drained by first barrier)
    const u16* wsrc = wb + (size_t)cb * 32768;
    #pragma unroll
    for (int q = 0; q < 16; ++q) {
        const int idx = q * 256 + tid;
        __builtin_amdgcn_global_load_lds(
            (glob_u*)(wsrc + (size_t)idx * 8),
            (lds_u*)((char*)&Bs[0] + idx * 16), 16, 0, 0);
    }

    const int rhalf = wv & 1, chalf = wv >> 1;
    const int c_lane = l & 31;
    const int col0 = cb * 128 + chalf * 64 + c_lane;
    const int col1 = col0 + 32;
    const float w20 = w2v[col0], w21 = w2v[col1];   // d_ws loads (fast)

    for (int rbi = 0; rbi < 4; ++rbi) {
        const int rb = rbg * 4 + rbi;
        __syncthreads();              // protect sx2/sthr/As reuse across rbi
        if (tid < 128) sx2[tid] = x2v[rb * 128 + tid];   // d_ws (fast)
        if (COLLECT && wv == 0)       // thr chunk via LDS DMA (d_out)
            __builtin_amdgcn_global_load_lds(
                (glob_u*)(thr + rb * 128 + l * 4),
                (lds_u*)((char*)&sthr[0] + l * 16), 16, 0, 0);
        {   // stage A chunk kt=0 into buf 0
            const size_t src = ((size_t)(rb * 4 + wv) * 16 + 0) * 64 + l;
            __builtin_amdgcn_global_load_lds(
                (glob_u*)(zb + src * 8),
                (lds_u*)((char*)&As[0][0] + tid * 16), 16, 0, 0);
        }
        __syncthreads();              // drains B(+first rbi)/A0/thr DMA

        f32x16 acc00 = {}, acc01 = {}, acc10 = {}, acc11 = {};
        for (int kt = 0; kt < 16; ++kt) {
            const int cur = kt & 1;
            if (kt + 1 < 16) {        // prefetch next A chunk
                const size_t src =
                    ((size_t)(rb * 4 + wv) * 16 + (kt + 1)) * 64 + l;
                __builtin_amdgcn_global_load_lds(
                    (glob_u*)(zb + src * 8),
                    (lds_u*)((char*)&As[cur ^ 1][0] + tid * 16), 16, 0, 0);
            }
            const short8 a0 = As[cur][(rhalf * 2) * 64 + l];
            const short8 a1 = As[cur][(rhalf * 2 + 1) * 64 + l];
            const short8 b0 = Bs[(chalf * 2) * 1024 + kt * 64 + l];
            const short8 b1 = Bs[(chalf * 2 + 1) * 1024 + kt * 64 + l];
            acc00 = __builtin_amdgcn_mfma_f32_32x32x16_bf16(a0, b0, acc00, 0, 0, 0);
            acc01 = __builtin_amdgcn_mfma_f32_32x32x16_bf16(a0, b1, acc01, 0, 0, 0);
            acc10 = __builtin_amdgcn_mfma_f32_32x32x16_bf16(a1, b0, acc10, 0, 0, 0);
            acc11 = __builtin_amdgcn_mfma_f32_32x32x16_bf16(a1, b1, acc11, 0, 0, 0);
            __syncthreads();          // drains A prefetch + releases buffers
        }

        // epilogue: dist math verbatim R12 (HW-verified C/D mapping)
        #pragma unroll
        for (int r = 0; r < 16; ++r) {
            const int cr  = (r & 3) + 8 * (r >> 2) + 4 * (l >> 5);
            const int rl0 = rhalf * 64 + cr;
            const int rl1 = rl0 + 32;
            const float x20 = sx2[rl0], x21 = sx2[rl1];
            const float d00 = __fadd_rn(__fsub_rn(x20, __fmul_rn(2.0f, acc00[r])), w20);
            const float d01 = __fadd_rn(__fsub_rn(x20, __fmul_rn(2.0f, acc01[r])), w21);
            const float d10 = __fadd_rn(__fsub_rn(x21, __fmul_rn(2.0f, acc10[r])), w20);
            const float d11 = __fadd_rn(__fsub_rn(x21, __fmul_rn(2.0f, acc11[r])), w21);
            if (!COLLECT) {
                float m0 = fminf(d00, d01);
                float m1 = fminf(d10, d11);
                #pragma unroll
                for (int off = 1; off <= 16; off <<= 1) {   // within 32-half
                    m0 = fminf(m0, __shfl_xor(m0, off, 64));
                    m1 = fminf(m1, __shfl_xor(m1, off, 64));
                }
                if (c_lane == 0) {
                    atomicMin(&thrmin[rb * 128 + rl0], fkey(m0));
                    atomicMin(&thrmin[rb * 128 + rl1], fkey(m1));
                }
            } else {
                const float t0 = sthr[rl0], t1 = sthr[rl1];
                const u32 rg0 = rb * 128 + rl0, rg1 = rb * 128 + rl1;
                if (d00 <= t0) { int p = atomicAdd(counter, 1);
                    if (p < CAP) list[p] = (rg0 << 13) | col0; }
                if (d01 <= t0) { int p = atomicAdd(counter, 1);
                    if (p < CAP) list[p] = (rg0 << 13) | col1; }
                if (d10 <= t1) { int p = atomicAdd(counter, 1);
                    if (p < CAP) list[p] = (rg1 << 13) | col0; }
                if (d11 <= t1) { int p = atomicAdd(counter, 1);
                    if (p < CAP) list[p] = (rg1 << 13) | col1; }
            }
        }
    }
}

// ---------------- thr[row] = unkey(min) + sound 2E margin (all-ws) --------
__global__ __launch_bounds__(256) void k_minred(const u32* __restrict__ thrmin,
                                                const float* __restrict__ x2v,
                                                const float* __restrict__ w2max,
                                                float* __restrict__ thr) {
    const int row = blockIdx.x * 256 + threadIdx.x;
    const u32 u = thrmin[row];
    const float m = (u >> 31) ? __uint_as_float(u ^ 0x80000000u)
                              : __uint_as_float(~u);
    thr[row] = m + (0.0334f * sqrtf(x2v[row] * (*w2max)) + 4e-4f);
}

// ---------------- exact re-rank of candidates (verbatim R12) ---------------
__global__ __launch_bounds__(256) void k_rerank(
        const float* __restrict__ z, const float* __restrict__ w,
        const float* __restrict__ x2v, const float* __restrict__ w2v,
        const u32* __restrict__ list, const int* __restrict__ counter,
        u64* __restrict__ best) {
    const int l = threadIdx.x & 63, wv = threadIdx.x >> 6;
    const int cnt = min(*counter, CAP);
    const int stride = gridDim.x * 4;
    for (int c = blockIdx.x * 4 + wv; c < cnt; c += stride) {
        const u32 e = list[c];
        const int row = e >> 13, col = e & 8191;
        const float4 va = *(const float4*)(z + (size_t)row * DD + l * 4);
        const float4 vb = *(const float4*)(w + (size_t)col * DD + l * 4);
        float xe = 0.0f;
        for (int d4 = 0; d4 < 64; ++d4) {      // d = 4*d4 + {0,1,2,3} asc
            xe = __fmaf_rn(__shfl(va.x, d4), __shfl(vb.x, d4), xe);
            xe = __fmaf_rn(__shfl(va.y, d4), __shfl(vb.y, d4), xe);
            xe = __fmaf_rn(__shfl(va.z, d4), __shfl(vb.z, d4), xe);
            xe = __fmaf_rn(__shfl(va.w, d4), __shfl(vb.w, d4), xe);
        }
        const float dv = __fadd_rn(
            __fsub_rn(x2v[row], __fmul_rn(2.0f, xe)), w2v[col]);
        if (l == 0)
            atomicMin(best + row, ((u64)fkey(dv) << 32) | (u64)(u32)col);
    }
}

// ---------------- extract idx + init EMA outputs + zero loss ---------------
__global__ __launch_bounds__(256) void k_init(const float* __restrict__ emaw,
                                              const float* __restrict__ ecs,
                                              float* __restrict__ out,
                                              float* __restrict__ lossacc,
                                              const u64* __restrict__ best,
                                              int* __restrict__ idx_ws) {
    const int i = blockIdx.x * 256 + threadIdx.x;    // grid covers KC*DD = 2M
    if (i < NTOK) {
        const int code = (int)(best[i] & 8191ull);
        idx_ws[i] = code;
        out[OFF_IDX + i] = (float)code;
    }
    out[OFF_EMA + i] = __fmul_rn(DECAY_F, emaw[i]);
    if (i < KC) out[OFF_CS + i] = __fmul_rn(DECAY_F, ecs[i]);
    if (i == 0) *lossacc = 0.0f;
}

// ---------------- gather quantized + loss partial + EMA scatter ------------
__global__ __launch_bounds__(256) void k_scatter(const float* __restrict__ z,
                                                 const float* __restrict__ w,
                                                 const int* __restrict__ idx_ws,
                                                 float* __restrict__ out,
                                                 float* __restrict__ lossacc) {
    const int n = blockIdx.x, d = threadIdx.x;
    const int k = idx_ws[n];
    const float zv   = z[n * DD + d];
    const float q    = w[k * DD + d];
    const float diff = __fsub_rn(q, zv);
    out[OFF_Q + n * DD + d] = __fadd_rn(zv, diff);   // straight-through value

    float s = __fmul_rn(diff, diff);
    #pragma unroll
    for (int off = 32; off; off >>= 1) s += __shfl_down(s, off, 64);
    __shared__ float ps[4];
    if ((d & 63) == 0) ps[d >> 6] = s;
    __syncthreads();
    if (d == 0) atomicAdd(lossacc, ps[0] + ps[1] + ps[2] + ps[3]);

    atomicAdd(&out[OFF_EMA + k * DD + d], __fmul_rn(OMD_F, zv));
    if (d == 0) atomicAdd(&out[OFF_CS + k], OMD_F);
}

// ---------------- n = sum(new_cluster_size); finalize loss -----------------
__global__ __launch_bounds__(256) void k_nsum(float* __restrict__ out,
                                              const float* __restrict__ lossacc,
                                              float* __restrict__ nsum) {
    const int t = threadIdx.x;
    float s = 0.0f;
    for (int i = t; i < KC; i += 256) s += out[OFF_CS + i];
    #pragma unroll
    for (int off = 32; off; off >>= 1) s += __shfl_down(s, off, 64);
    __shared__ float ps[4];
    if ((t & 63) == 0) ps[t >> 6] = s;
    __syncthreads();
    if (t == 0) {
        *nsum = ps[0] + ps[1] + ps[2] + ps[3];
        out[OFF_LOSS] = 1.25f * (*lossacc) / 4194304.0f;
    }
}

// ---------------- new_weight = new_ema_w / laplace(cluster_size) -----------
__global__ __launch_bounds__(256) void k_neww(float* __restrict__ out,
                                              const float* __restrict__ nsum) {
    const int k = blockIdx.x, d = threadIdx.x;
    const float n  = *nsum;
    const float cs = __fmul_rn(__fdiv_rn(__fadd_rn(out[OFF_CS + k], EPS_F),
                                         __fadd_rn(n, KEPS_F)), n);
    out[OFF_W + k * DD + d] = __fdiv_rn(out[OFF_EMA + k * DD + d], cs);
}

extern "C" void kernel_launch(void* const* d_in, const int* in_sizes, int n_in,
                              void* d_out, int out_size, void* d_ws, size_t ws_size,
                              hipStream_t stream) {
    const float* z    = (const float*)d_in[0];
    const float* w    = (const float*)d_in[1];
    const float* ecs  = (const float*)d_in[2];
    const float* emaw = (const float*)d_in[3];
    float* out = (float*)d_out;

    // small scratch in ws (~164 KB, same budget that always passed)
    int*   idx_ws  = (int*)d_ws;                       // NTOK ints
    float* x2v     = (float*)d_ws + NTOK;              // NTOK floats
    float* w2v     = x2v + NTOK;                       // KC floats
    float* lossacc = w2v + KC;                         // 1 float
    float* nsum    = lossacc + 1;                      // 1 float
    int*   counter = (int*)(nsum + 1);                 // 1 int
    float* w2max   = (float*)(counter + 1);            // 1 float
    u32*   thrmin  = (u32*)idx_ws;   // aliases idx_ws: read by k_minred
                                     // BEFORE k_init writes idx_ws (safe)

    // big scratch inside not-yet-final d_out regions (Q region = 16 MB):
    // zb frag 0-8MB | wb frag 8-12MB | list 12-15MB | best64 @15MB (128KB)
    u16* zb     = (u16*)d_out;                               // byte 0
    u16* wb     = (u16*)((char*)d_out + 8388608);            // byte 8 MB
    u32* list   = (u32*)((char*)d_out + 12582912);           // byte 12 MB
    u64* best64 = (u64*)((char*)d_out + 15728640);           // byte 15 MB
    float* thr  = out + OFF_W;     // NTOK thresholds (64 KB, d_out)

    k_rownorm<<<NTOK / 16, 256, 0, stream>>>(z, x2v);
    k_rownorm<<<KC / 16,   256, 0, stream>>>(w, w2v);
    k_w2max  <<<1,         256, 0, stream>>>(w2v, w2max, counter);
    k_cvt    <<<2048,      256, 0, stream>>>(z, zb, 512, best64, NTOK, thrmin);
    k_cvt    <<<1024,      256, 0, stream>>>(w, wb, 256, (u64*)0, 0, (u32*)0);
    k_mfma<0><<<2048,      256, 0, stream>>>(zb, wb, x2v, w2v, thr, thrmin,
                                             list, counter);
    k_minred <<<NTOK / 256, 256, 0, stream>>>(thrmin, x2v, w2max, thr);
    k_mfma<1><<<2048,      256, 0, stream>>>(zb, wb, x2v, w2v, thr, thrmin,
                                             list, counter);
    k_rerank <<<512,       256, 0, stream>>>(z, w, x2v, w2v, list, counter,
                                             best64);
    k_init   <<<(KC * DD) / 256, 256, 0, stream>>>(emaw, ecs, out, lossacc,
                                                   best64, idx_ws);
    k_scatter<<<NTOK,      256, 0, stream>>>(z, w, idx_ws, out, lossacc);
    k_nsum   <<<1,         256, 0, stream>>>(out, lossacc, nsum);
    k_neww   <<<KC,        256, 0, stream>>>(out, nsum);
}

// Round 12
// 1311.502 us; speedup vs baseline: 1.6019x; 1.6019x over previous
//
#include <hip/hip_runtime.h>

// VQ-VAE VectorQuantizer forward + EMA update, MI355X (gfx950).
// Distance argmin bit-exactly emulates the numpy fp32 reference:
//   dist = pairwise_sum(x*x) - 2*(sgemm single-FMA-chain) + pairwise_sum(w*w)
// R2-R8: fp32 K-split GEMM ladder -> best 810us k_argmin (R8: pk_fma),
//   total 1114us. Dual 437us walls (FMA issue + LDS delivery) => ~1.85x.
// R10-R13: bf16-MFMA filter + exact re-rank. PASSED (bit-exact) but k_mfma
//   pinned at 1043-1047us across 3 structurally different bodies and 4x
//   grid change, all pipes <3% busy (MFMA work itself = 27us). Fixed wall,
//   mechanism not exposed by SQ/TCC counters. ABANDONED; reverted to R8.
// R14: R8 compute verbatim + launch-count reduction (aux was ~304us vs
//   ~60us roofline => inter-dispatch gaps dominate):
//   - k_prep: tr(z)+tr(w)+rownorm(z)+rownorm(w) fused (7680 blocks).
//   - k_reduce fused into k_argmin (per-rb last-block, threadfence pattern).
//   - k_nsum fused into k_scatter (global last-block, same sum order).
//   10 launches -> 5. All arithmetic chains byte-identical => bit-exact.

#define NTOK 16384
#define KC   8192
#define DD   256

#define OFF_Q    0
#define OFF_LOSS 4194304
#define OFF_IDX  4194305
#define OFF_W    4210689
#define OFF_CS   6307841
#define OFF_EMA  6316033

#define DECAY_F  0.99f
#define OMD_F    0.01f
#define EPS_F    1e-5f
#define KEPS_F   0.08192f   // K * eps

#define SPLIT    16
#define NSTEP    64         // (KC/SPLIT/128) kt-tiles * 16 d-chunks

typedef __attribute__((address_space(3))) unsigned int lds_u;
typedef const __attribute__((address_space(1))) unsigned int glob_u;
typedef float v2f __attribute__((ext_vector_type(2)));
typedef union { float4 f4; v2f h[2]; } f4u;

// ---------------- fused prep: transposes + row-norms + counter zero --------
// blocks [0,4096): tr z->zT; [4096,6144): tr w->wT;
// [6144,7168): rownorm z->x2v; [7168,7680): rownorm w->w2v.
// Bodies verbatim from the passing R8 kernels (bit-exact).
__global__ __launch_bounds__(256) void k_prep(const float* __restrict__ z,
                                              const float* __restrict__ w,
                                              float* __restrict__ zT,
                                              float* __restrict__ wT,
                                              float* __restrict__ x2v,
                                              float* __restrict__ w2v,
                                              int* __restrict__ argmin_done) {
    __shared__ float s[32][33];
    const int b = blockIdx.x, tid = threadIdx.x;
    if (b == 0 && tid < 128) argmin_done[tid] = 0;

    if (b < 6144) {
        // ---- 32x32 LDS transpose (coalesced both sides) ----
        const float* in;
        float* outT;
        int R, bx, by;
        if (b < 4096) { in = z; outT = zT; R = NTOK; bx = b & 7; by = b >> 3; }
        else { const int b2 = b - 4096;
               in = w; outT = wT; R = KC;   bx = b2 & 7; by = b2 >> 3; }
        const int tx = tid & 31, ty = tid >> 5;
        const int c0 = bx * 32, r0 = by * 32;
        #pragma unroll
        for (int i = 0; i < 4; ++i)
            s[ty + i * 8][tx] = in[(size_t)(r0 + ty + i * 8) * DD + c0 + tx];
        __syncthreads();
        #pragma unroll
        for (int i = 0; i < 4; ++i)
            outT[(size_t)(c0 + ty + i * 8) * R + r0 + tx] = s[tx][ty + i * 8];
    } else {
        // ---- numpy-pairwise row squared-norms (n=256): bit-exact ----
        const float* a;
        float* outn;
        int blk;
        if (b < 7168) { a = z; outn = x2v; blk = b - 6144; }
        else          { a = w; outn = w2v; blk = b - 7168; }
        const int wave = tid >> 6, lane = tid & 63;
        const int row  = blk * 16 + wave * 4 + (lane >> 4);
        const int p    = lane & 15;
        const int h    = p >> 3, j = p & 7;
        const float* base = a + row * DD + h * 128 + j;
        float v = base[0];
        float r = __fmul_rn(v, v);
        #pragma unroll
        for (int t = 1; t < 16; ++t) {
            v = base[8 * t];
            r = __fadd_rn(r, __fmul_rn(v, v));
        }
        r = __fadd_rn(r, __shfl_xor(r, 1));
        r = __fadd_rn(r, __shfl_xor(r, 2));
        r = __fadd_rn(r, __shfl_xor(r, 4));
        r = __fadd_rn(r, __shfl_xor(r, 8));
        if (p == 0) outn[row] = r;
    }
}

// ---------------- argmin: K-split fp32 GEMM (R8 body) + fused reduce -------
// grid = 2048: split = blockIdx&15 (split&7 = XCD id), rb = blockIdx>>4.
// 128x128 tiles, 8x8 acc as v2f pairs via v_pk_fma_f32 (two independent
// IEEE fp32 FMAs/inst; rounding == v_fma_f32 => bit-exact chain, k asc).
// After candidate writes: the LAST block of each rb-group (atomicAdd on
// argmin_done[rb] + threadfence) reduces that rb's 16 split-candidates
// per row -> idx_ws + OFF_IDX (comparator verbatim k_reduce).
__global__ __launch_bounds__(256, 4) void k_argmin(
        const float* __restrict__ zT, const float* __restrict__ wT,
        const float* __restrict__ x2v, const float* __restrict__ w2v,
        float* __restrict__ vbuf, int* __restrict__ kbuf,
        int* __restrict__ idx_ws, float* __restrict__ out,
        int* __restrict__ argmin_done) {
    __shared__ float Zs[2][16][128];   // [buf][d][row]  2 x 8 KB
    __shared__ float Ws[2][16][128];   // [buf][d][code] 2 x 8 KB
    __shared__ int lastf;

    const int tid   = threadIdx.x;
    const int split = blockIdx.x & 15;
    const int rb    = blockIdx.x >> 4;
    const int n0    = rb * 128;
    const int cbase = split * 512;
    const int tx4   = (tid & 15) * 4;
    const int ty4   = (tid >> 4) * 4;
    const int l     = tid & 63;
    const int wv    = tid >> 6;
    const int col   = (l & 31) * 4;

    float bestv[8];
    int   bestk[8];
    #pragma unroll
    for (int i = 0; i < 8; ++i) { bestv[i] = 1e30f; bestk[i] = 0; }

    v2f acc[8][4];

    auto stage = [&](int s, int b) {
        const int d0 = (s & 15) * 16;
        const int c0 = cbase + (s >> 4) * 128;
        #pragma unroll
        for (int q = 0; q < 2; ++q) {
            const int r  = wv * 4 + 2 * q;      // wave-uniform base row
            const int rr = r + (l >> 5);        // per-lane row
            const float* gz = zT + (size_t)(d0 + rr) * NTOK + n0 + col;
            const float* gw = wT + (size_t)(d0 + rr) * KC   + c0 + col;
            __builtin_amdgcn_global_load_lds(
                (glob_u*)gz,
                (lds_u*)((char*)&Zs[b][0][0] + r * 512 + l * 16), 16, 0, 0);
            __builtin_amdgcn_global_load_lds(
                (glob_u*)gw,
                (lds_u*)((char*)&Ws[b][0][0] + r * 512 + l * 16), 16, 0, 0);
        }
    };

    stage(0, 0);
    __syncthreads();

    for (int s = 0; s < NSTEP; ++s) {
        const int cur = s & 1;

        if ((s & 15) == 0) {
            #pragma unroll
            for (int i = 0; i < 8; ++i)
                #pragma unroll
                for (int jp = 0; jp < 4; ++jp) acc[i][jp] = (v2f)(0.0f);
        }

        if (s + 1 < NSTEP) stage(s + 1, cur ^ 1);   // prefetch next chunk

        #pragma unroll 8
        for (int dd = 0; dd < 16; ++dd) {
            f4u A0, A1, B0, B1;
            A0.f4 = *(const float4*)&Zs[cur][dd][ty4];
            A1.f4 = *(const float4*)&Zs[cur][dd][64 + ty4];
            B0.f4 = *(const float4*)&Ws[cur][dd][tx4];
            B1.f4 = *(const float4*)&Ws[cur][dd][64 + tx4];
            // v_pk_fma_f32: A-broadcast via op_sel (no splat movs).
#define PKLO(ACC, A, B) asm("v_pk_fma_f32 %0, %1, %2, %0 op_sel:[0,0,0] op_sel_hi:[0,1,1]" \
                            : "+v"(ACC) : "v"(A), "v"(B))
#define PKHI(ACC, A, B) asm("v_pk_fma_f32 %0, %1, %2, %0 op_sel:[1,0,0] op_sel_hi:[1,1,1]" \
                            : "+v"(ACC) : "v"(A), "v"(B))
#define PK4(MAC, I, AP)                \
            MAC(acc[I][0], AP, B0.h[0]); \
            MAC(acc[I][1], AP, B0.h[1]); \
            MAC(acc[I][2], AP, B1.h[0]); \
            MAC(acc[I][3], AP, B1.h[1]);
            PK4(PKLO, 0, A0.h[0])
            PK4(PKHI, 1, A0.h[0])
            PK4(PKLO, 2, A0.h[1])
            PK4(PKHI, 3, A0.h[1])
            PK4(PKLO, 4, A1.h[0])
            PK4(PKHI, 5, A1.h[0])
            PK4(PKLO, 6, A1.h[1])
            PK4(PKHI, 7, A1.h[1])
#undef PK4
#undef PKHI
#undef PKLO
        }

        if ((s & 15) == 15) {
            // dist = (x2 - 2*xe) + w2, per-op fp32 rounding; (==, k<)
            // tie-break == np.argmin first-occurrence.
            const int c0 = cbase + (s >> 4) * 128;
            #pragma unroll
            for (int j = 0; j < 8; ++j) {
                const int   jp   = j >> 1;
                const int   code = c0 + ((j < 4) ? (tx4 + j) : (64 + tx4 + j - 4));
                const float w2   = w2v[code];
                #pragma unroll
                for (int i = 0; i < 8; ++i) {
                    const int   row = n0 + ((i < 4) ? (ty4 + i) : (64 + ty4 + i - 4));
                    const float x2  = x2v[row];
                    const float xe  = (j & 1) ? acc[i][jp].y : acc[i][jp].x;
                    const float dv  = __fadd_rn(
                        __fsub_rn(x2, __fmul_rn(2.0f, xe)), w2);
                    if (dv < bestv[i] || (dv == bestv[i] && code < bestk[i])) {
                        bestv[i] = dv; bestk[i] = code;
                    }
                }
            }
        }

        __syncthreads();   // drains prefetch vmcnt + LDS reads
    }

    // reduce across tx (16 consecutive lanes share ty)
    #pragma unroll
    for (int i = 0; i < 8; ++i) {
        float bv = bestv[i];
        int   bk = bestk[i];
        #pragma unroll
        for (int off = 8; off; off >>= 1) {
            const float ov = __shfl_down(bv, off, 16);
            const int   ok = __shfl_down(bk, off, 16);
            if (ov < bv || (ov == bv && ok < bk)) { bv = ov; bk = ok; }
        }
        if ((tid & 15) == 0) {
            const int row = n0 + ((i < 4) ? (ty4 + i) : (64 + ty4 + i - 4));
            vbuf[split * NTOK + row] = bv;
            kbuf[split * NTOK + row] = bk;
        }
    }

    // ---- fused k_reduce: last block of this rb-group combines 16 splits ---
    __syncthreads();                         // all candidate writes issued
    if (tid == 0) {
        __threadfence();                     // publish this block's writes
        lastf = (atomicAdd(&argmin_done[rb], 1) == SPLIT - 1);
    }
    __syncthreads();
    if (lastf) {
        __threadfence();                     // acquire others' writes
        if (tid < 128) {
            const int row = n0 + tid;
            float bv = vbuf[row];
            int   bk = kbuf[row];
            #pragma unroll
            for (int s = 1; s < SPLIT; ++s) {
                const float v = vbuf[s * NTOK + row];
                const int   k = kbuf[s * NTOK + row];
                if (v < bv || (v == bv && k < bk)) { bv = v; bk = k; }
            }
            idx_ws[row] = bk;
            out[OFF_IDX + row] = (float)bk;
        }
    }
}

// ---------------- init EMA outputs + zero loss/done (after argmin) ---------
__global__ __launch_bounds__(256) void k_init(const float* __restrict__ emaw,
                                              const float* __restrict__ ecs,
                                              float* __restrict__ out,
                                              float* __restrict__ lossacc,
                                              int* __restrict__ scatter_done) {
    const int i = blockIdx.x * 256 + threadIdx.x;    // grid covers KC*DD = 2M
    out[OFF_EMA + i] = __fmul_rn(DECAY_F, emaw[i]);
    if (i < KC) out[OFF_CS + i] = __fmul_rn(DECAY_F, ecs[i]);
    if (i == 0) { *lossacc = 0.0f; *scatter_done = 0; }
}

// ---------------- gather + loss + EMA scatter + fused nsum/loss finalize ---
__global__ __launch_bounds__(256) void k_scatter(const float* __restrict__ z,
                                                 const float* __restrict__ w,
                                                 const int* __restrict__ idx_ws,
                                                 float* __restrict__ out,
                                                 float* __restrict__ lossacc,
                                                 int* __restrict__ scatter_done,
                                                 float* __restrict__ nsum) {
    const int n = blockIdx.x, d = threadIdx.x;
    const int k = idx_ws[n];
    const float zv   = z[n * DD + d];
    const float q    = w[k * DD + d];
    const float diff = __fsub_rn(q, zv);
    out[OFF_Q + n * DD + d] = __fadd_rn(zv, diff);   // straight-through value

    float s = __fmul_rn(diff, diff);
    #pragma unroll
    for (int off = 32; off; off >>= 1) s += __shfl_down(s, off, 64);
    __shared__ float ps[4];
    __shared__ int lastf;
    if ((d & 63) == 0) ps[d >> 6] = s;
    __syncthreads();
    if (d == 0) atomicAdd(lossacc, ps[0] + ps[1] + ps[2] + ps[3]);

    atomicAdd(&out[OFF_EMA + k * DD + d], __fmul_rn(OMD_F, zv));
    if (d == 0) atomicAdd(&out[OFF_CS + k], OMD_F);

    // ---- fused k_nsum: globally-last block sums CS + finalizes loss -------
    __syncthreads();                         // all this block's atomics issued
    if (d == 0) {
        __threadfence();                     // publish before retiring
        lastf = (atomicAdd(scatter_done, 1) == NTOK - 1);
    }
    __syncthreads();
    if (lastf) {
        __threadfence();                     // acquire all blocks' atomics
        float t = 0.0f;
        for (int i = d; i < KC; i += 256) t += out[OFF_CS + i];
        #pragma unroll
        for (int off = 32; off; off >>= 1) t += __shfl_down(t, off, 64);
        if ((d & 63) == 0) ps[d >> 6] = t;
        __syncthreads();
        if (d == 0) {
            *nsum = ps[0] + ps[1] + ps[2] + ps[3];
            out[OFF_LOSS] = 1.25f * (*lossacc) / 4194304.0f;
        }
    }
}

// ---------------- new_weight = new_ema_w / laplace(cluster_size) -----------
__global__ __launch_bounds__(256) void k_neww(float* __restrict__ out,
                                              const float* __restrict__ nsum) {
    const int k = blockIdx.x, d = threadIdx.x;
    const float n  = *nsum;
    const float cs = __fmul_rn(__fdiv_rn(__fadd_rn(out[OFF_CS + k], EPS_F),
                                         __fadd_rn(n, KEPS_F)), n);
    out[OFF_W + k * DD + d] = __fdiv_rn(out[OFF_EMA + k * DD + d], cs);
}

extern "C" void kernel_launch(void* const* d_in, const int* in_sizes, int n_in,
                              void* d_out, int out_size, void* d_ws, size_t ws_size,
                              hipStream_t stream) {
    const float* z    = (const float*)d_in[0];
    const float* w    = (const float*)d_in[1];
    const float* ecs  = (const float*)d_in[2];
    const float* emaw = (const float*)d_in[3];
    float* out = (float*)d_out;

    // small scratch in ws (~165 KB)
    int*   idx_ws       = (int*)d_ws;                  // NTOK ints
    float* x2v          = (float*)d_ws + NTOK;         // NTOK floats
    float* w2v          = x2v + NTOK;                  // KC floats
    float* lossacc      = w2v + KC;                    // 1 float
    float* nsum         = lossacc + 1;                 // 1 float
    int*   argmin_done  = (int*)(nsum + 1);            // 128 ints
    int*   scatter_done = argmin_done + 128;           // 1 int

    // big scratch inside not-yet-final d_out regions:
    float* zT   = out + OFF_Q;     // 16384x256 -> 256x16384 (16 MB)
    float* wT   = out + OFF_W;     //  8192x256 -> 256x8192  ( 8 MB)
    float* vbuf = out + OFF_EMA;                        // SPLIT*NTOK floats
    int*   kbuf = (int*)(out + OFF_EMA) + SPLIT * NTOK; // SPLIT*NTOK ints

    k_prep   <<<7680,  256, 0, stream>>>(z, w, zT, wT, x2v, w2v, argmin_done);
    k_argmin <<<SPLIT * (NTOK / 128), 256, 0, stream>>>(zT, wT, x2v, w2v,
                                                        vbuf, kbuf, idx_ws,
                                                        out, argmin_done);
    k_init   <<<(KC * DD) / 256, 256, 0, stream>>>(emaw, ecs, out, lossacc,
                                                   scatter_done);
    k_scatter<<<NTOK,  256, 0, stream>>>(z, w, idx_ws, out, lossacc,
                                         scatter_done, nsum);
    k_neww   <<<KC,    256, 0, stream>>>(out, nsum);
}

// Round 13
// 1088.077 us; speedup vs baseline: 1.9309x; 1.2053x over previous
//
#include <hip/hip_runtime.h>

// VQ-VAE VectorQuantizer forward + EMA update, MI355X (gfx950).
// Distance argmin bit-exactly emulates the numpy fp32 reference:
//   dist = pairwise_sum(x*x) - 2*(sgemm single-FMA-chain) + pairwise_sum(w*w)
// R2-R8: fp32 K-split GEMM ladder -> best 810us k_argmin (R8 pk_fma),
//   total 1114us. R10-R13 (MFMA filter): fixed 1043us wall, abandoned.
// R14: launch fusion (threadfence last-block patterns) REGRESSED both
//   k_argmin (+65us, per-block device fences) and aux (304->436us).
//   Separate-kernel structure restored verbatim from R8.
// R15: occupancy experiment on the R8 body: d-chunk 16 -> 8 rows halves
//   LDS to 16KB (2x[2][8][128] f32) -> blocks/CU cap rises 5 -> 8 (wave
//   cap), attacking the 23% barrier-idle seen at 36% occupancy. Steps
//   double (NSTEP 128), barriers double; more resident waves cover the
//   drains. K-walk unchanged: kt = s>>5, d = (s&31)*8 + dd ascending ->
//   single fp32 FMA chain per (row,code) => bit-exact argmin.

#define NTOK 16384
#define KC   8192
#define DD   256

#define OFF_Q    0
#define OFF_LOSS 4194304
#define OFF_IDX  4194305
#define OFF_W    4210689
#define OFF_CS   6307841
#define OFF_EMA  6316033

#define DECAY_F  0.99f
#define OMD_F    0.01f
#define EPS_F    1e-5f
#define KEPS_F   0.08192f   // K * eps

#define SPLIT    16
#define NSTEP    128        // 4 code-tiles x 32 8-row d-chunks

typedef __attribute__((address_space(3))) unsigned int lds_u;
typedef const __attribute__((address_space(1))) unsigned int glob_u;
typedef float v2f __attribute__((ext_vector_type(2)));
typedef union { float4 f4; v2f h[2]; } f4u;

// ---------------- 32x32 LDS transpose (coalesced both sides) ---------------
__global__ __launch_bounds__(256) void k_tr(const float* __restrict__ in,
                                            float* __restrict__ outT,
                                            int R, int C) {
    __shared__ float s[32][33];
    const int tx = threadIdx.x & 31, ty = threadIdx.x >> 5;
    const int c0 = blockIdx.x * 32, r0 = blockIdx.y * 32;
    #pragma unroll
    for (int i = 0; i < 4; ++i)
        s[ty + i * 8][tx] = in[(size_t)(r0 + ty + i * 8) * C + c0 + tx];
    __syncthreads();
    #pragma unroll
    for (int i = 0; i < 4; ++i)
        outT[(size_t)(c0 + ty + i * 8) * R + r0 + tx] = s[tx][ty + i * 8];
}

// ---- numpy-pairwise row squared-norms (n=256): two 128 halves, 8 strided
// accumulators each, butterfly combine — bit-exact vs numpy pairwise sum.
__global__ __launch_bounds__(256) void k_rownorm(const float* __restrict__ a,
                                                 float* __restrict__ outn) {
    const int wave = threadIdx.x >> 6, lane = threadIdx.x & 63;
    const int row  = blockIdx.x * 16 + wave * 4 + (lane >> 4);
    const int p    = lane & 15;
    const int h    = p >> 3, j = p & 7;
    const float* base = a + row * DD + h * 128 + j;
    float v = base[0];
    float r = __fmul_rn(v, v);
    #pragma unroll
    for (int t = 1; t < 16; ++t) {
        v = base[8 * t];
        r = __fadd_rn(r, __fmul_rn(v, v));
    }
    r = __fadd_rn(r, __shfl_xor(r, 1));
    r = __fadd_rn(r, __shfl_xor(r, 2));
    r = __fadd_rn(r, __shfl_xor(r, 4));
    r = __fadd_rn(r, __shfl_xor(r, 8));
    if (p == 0) outn[row] = r;
}

// ---------------- argmin: K-split fp32 GEMM, 128 rows x 128 codes/tile -----
// grid = 2048: split = blockIdx&15 (split&7 = XCD id), rb = blockIdx>>4.
// 128 steps of 8-row d-chunks (16KB LDS dbuf -> 8 blocks/CU cap), one
// __syncthreads per step. 8x8 acc as v2f pairs via v_pk_fma_f32 (two
// independent IEEE fp32 FMAs/inst, rounding == v_fma_f32).
__global__ __launch_bounds__(256, 4) void k_argmin(
        const float* __restrict__ zT, const float* __restrict__ wT,
        const float* __restrict__ x2v, const float* __restrict__ w2v,
        float* __restrict__ vbuf, int* __restrict__ kbuf) {
    __shared__ float Zs[2][8][128];    // [buf][d][row]  2 x 4 KB
    __shared__ float Ws[2][8][128];    // [buf][d][code] 2 x 4 KB

    const int tid   = threadIdx.x;
    const int split = blockIdx.x & 15;
    const int rb    = blockIdx.x >> 4;
    const int n0    = rb * 128;
    const int cbase = split * 512;
    const int tx4   = (tid & 15) * 4;
    const int ty4   = (tid >> 4) * 4;
    const int l     = tid & 63;
    const int wv    = tid >> 6;
    const int col   = (l & 31) * 4;

    float bestv[8];
    int   bestk[8];
    #pragma unroll
    for (int i = 0; i < 8; ++i) { bestv[i] = 1e30f; bestk[i] = 0; }

    v2f acc[8][4];

    // stage step s into buffer b: 1 gz + 1 gw global_load_lds per thread
    // (wave wv covers d-rows {wv*2, wv*2+1}; lanes 0-31 row0, 32-63 row1)
    auto stage = [&](int s, int b) {
        const int d0 = (s & 31) * 8;
        const int c0 = cbase + (s >> 5) * 128;
        const int rr = wv * 2 + (l >> 5);   // per-lane d-row
        const float* gz = zT + (size_t)(d0 + rr) * NTOK + n0 + col;
        const float* gw = wT + (size_t)(d0 + rr) * KC   + c0 + col;
        __builtin_amdgcn_global_load_lds(
            (glob_u*)gz,
            (lds_u*)((char*)&Zs[b][0][0] + wv * 1024 + l * 16), 16, 0, 0);
        __builtin_amdgcn_global_load_lds(
            (glob_u*)gw,
            (lds_u*)((char*)&Ws[b][0][0] + wv * 1024 + l * 16), 16, 0, 0);
    };

    stage(0, 0);
    __syncthreads();

    for (int s = 0; s < NSTEP; ++s) {
        const int cur = s & 1;

        if ((s & 31) == 0) {
            #pragma unroll
            for (int i = 0; i < 8; ++i)
                #pragma unroll
                for (int jp = 0; jp < 4; ++jp) acc[i][jp] = (v2f)(0.0f);
        }

        if (s + 1 < NSTEP) stage(s + 1, cur ^ 1);   // prefetch next chunk

        #pragma unroll 8
        for (int dd = 0; dd < 8; ++dd) {
            f4u A0, A1, B0, B1;
            A0.f4 = *(const float4*)&Zs[cur][dd][ty4];
            A1.f4 = *(const float4*)&Zs[cur][dd][64 + ty4];
            B0.f4 = *(const float4*)&Ws[cur][dd][tx4];
            B1.f4 = *(const float4*)&Ws[cur][dd][64 + tx4];
            // v_pk_fma_f32: A-broadcast via op_sel (no splat movs).
#define PKLO(ACC, A, B) asm("v_pk_fma_f32 %0, %1, %2, %0 op_sel:[0,0,0] op_sel_hi:[0,1,1]" \
                            : "+v"(ACC) : "v"(A), "v"(B))
#define PKHI(ACC, A, B) asm("v_pk_fma_f32 %0, %1, %2, %0 op_sel:[1,0,0] op_sel_hi:[1,1,1]" \
                            : "+v"(ACC) : "v"(A), "v"(B))
#define PK4(MAC, I, AP)                \
            MAC(acc[I][0], AP, B0.h[0]); \
            MAC(acc[I][1], AP, B0.h[1]); \
            MAC(acc[I][2], AP, B1.h[0]); \
            MAC(acc[I][3], AP, B1.h[1]);
            PK4(PKLO, 0, A0.h[0])
            PK4(PKHI, 1, A0.h[0])
            PK4(PKLO, 2, A0.h[1])
            PK4(PKHI, 3, A0.h[1])
            PK4(PKLO, 4, A1.h[0])
            PK4(PKHI, 5, A1.h[0])
            PK4(PKLO, 6, A1.h[1])
            PK4(PKHI, 7, A1.h[1])
#undef PK4
#undef PKHI
#undef PKLO
        }

        if ((s & 31) == 31) {
            // dist = (x2 - 2*xe) + w2, per-op fp32 rounding; explicit (==, k<)
            // tie-break == np.argmin first-occurrence.
            const int c0 = cbase + (s >> 5) * 128;
            #pragma unroll
            for (int j = 0; j < 8; ++j) {
                const int   jp   = j >> 1;
                const int   code = c0 + ((j < 4) ? (tx4 + j) : (64 + tx4 + j - 4));
                const float w2   = w2v[code];
                #pragma unroll
                for (int i = 0; i < 8; ++i) {
                    const int   row = n0 + ((i < 4) ? (ty4 + i) : (64 + ty4 + i - 4));
                    const float x2  = x2v[row];
                    const float xe  = (j & 1) ? acc[i][jp].y : acc[i][jp].x;
                    const float dv  = __fadd_rn(
                        __fsub_rn(x2, __fmul_rn(2.0f, xe)), w2);
                    if (dv < bestv[i] || (dv == bestv[i] && code < bestk[i])) {
                        bestv[i] = dv; bestk[i] = code;
                    }
                }
            }
        }

        // drains the prefetch (vmcnt, issued before the FMA phase) and the
        // LDS reads (lgkmcnt); releases buffers.
        __syncthreads();
    }

    // reduce across tx (16 consecutive lanes share ty)
    #pragma unroll
    for (int i = 0; i < 8; ++i) {
        float bv = bestv[i];
        int   bk = bestk[i];
        #pragma unroll
        for (int off = 8; off; off >>= 1) {
            const float ov = __shfl_down(bv, off, 16);
            const int   ok = __shfl_down(bk, off, 16);
            if (ov < bv || (ov == bv && ok < bk)) { bv = ov; bk = ok; }
        }
        if ((tid & 15) == 0) {
            const int row = n0 + ((i < 4) ? (ty4 + i) : (64 + ty4 + i - 4));
            vbuf[split * NTOK + row] = bv;
            kbuf[split * NTOK + row] = bk;
        }
    }
}

// ---------------- combine the 16 split-candidates per row ------------------
__global__ __launch_bounds__(256) void k_reduce(const float* __restrict__ vbuf,
                                                const int* __restrict__ kbuf,
                                                int* __restrict__ idx_ws,
                                                float* __restrict__ out) {
    const int r = blockIdx.x * 256 + threadIdx.x;
    float bv = vbuf[r];
    int   bk = kbuf[r];
    #pragma unroll
    for (int s = 1; s < SPLIT; ++s) {
        const float v = vbuf[s * NTOK + r];
        const int   k = kbuf[s * NTOK + r];
        if (v < bv || (v == bv && k < bk)) { bv = v; bk = k; }
    }
    idx_ws[r] = bk;
    out[OFF_IDX + r] = (float)bk;
}

// ---------------- init EMA outputs + zero loss accumulator -----------------
// (runs AFTER k_reduce: OFF_EMA region doubles as vbuf/kbuf scratch)
__global__ __launch_bounds__(256) void k_init(const float* __restrict__ emaw,
                                              const float* __restrict__ ecs,
                                              float* __restrict__ out,
                                              float* __restrict__ lossacc) {
    const int i = blockIdx.x * 256 + threadIdx.x;    // grid covers KC*DD = 2M
    out[OFF_EMA + i] = __fmul_rn(DECAY_F, emaw[i]);
    if (i < KC) out[OFF_CS + i] = __fmul_rn(DECAY_F, ecs[i]);
    if (i == 0) *lossacc = 0.0f;
}

// ---------------- gather quantized + loss partial + EMA scatter ------------
__global__ __launch_bounds__(256) void k_scatter(const float* __restrict__ z,
                                                 const float* __restrict__ w,
                                                 const int* __restrict__ idx_ws,
                                                 float* __restrict__ out,
                                                 float* __restrict__ lossacc) {
    const int n = blockIdx.x, d = threadIdx.x;
    const int k = idx_ws[n];
    const float zv   = z[n * DD + d];
    const float q    = w[k * DD + d];
    const float diff = __fsub_rn(q, zv);
    out[OFF_Q + n * DD + d] = __fadd_rn(zv, diff);   // straight-through value

    float s = __fmul_rn(diff, diff);
    #pragma unroll
    for (int off = 32; off; off >>= 1) s += __shfl_down(s, off, 64);
    __shared__ float ps[4];
    if ((d & 63) == 0) ps[d >> 6] = s;
    __syncthreads();
    if (d == 0) atomicAdd(lossacc, ps[0] + ps[1] + ps[2] + ps[3]);

    atomicAdd(&out[OFF_EMA + k * DD + d], __fmul_rn(OMD_F, zv));
    if (d == 0) atomicAdd(&out[OFF_CS + k], OMD_F);
}

// ---------------- n = sum(new_cluster_size); finalize loss -----------------
__global__ __launch_bounds__(256) void k_nsum(float* __restrict__ out,
                                              const float* __restrict__ lossacc,
                                              float* __restrict__ nsum) {
    const int t = threadIdx.x;
    float s = 0.0f;
    for (int i = t; i < KC; i += 256) s += out[OFF_CS + i];
    #pragma unroll
    for (int off = 32; off; off >>= 1) s += __shfl_down(s, off, 64);
    __shared__ float ps[4];
    if ((t & 63) == 0) ps[t >> 6] = s;
    __syncthreads();
    if (t == 0) {
        *nsum = ps[0] + ps[1] + ps[2] + ps[3];
        out[OFF_LOSS] = 1.25f * (*lossacc) / 4194304.0f;
    }
}

// ---------------- new_weight = new_ema_w / laplace(cluster_size) -----------
__global__ __launch_bounds__(256) void k_neww(float* __restrict__ out,
                                              const float* __restrict__ nsum) {
    const int k = blockIdx.x, d = threadIdx.x;
    const float n  = *nsum;
    const float cs = __fmul_rn(__fdiv_rn(__fadd_rn(out[OFF_CS + k], EPS_F),
                                         __fadd_rn(n, KEPS_F)), n);
    out[OFF_W + k * DD + d] = __fdiv_rn(out[OFF_EMA + k * DD + d], cs);
}

extern "C" void kernel_launch(void* const* d_in, const int* in_sizes, int n_in,
                              void* d_out, int out_size, void* d_ws, size_t ws_size,
                              hipStream_t stream) {
    const float* z    = (const float*)d_in[0];
    const float* w    = (const float*)d_in[1];
    const float* ecs  = (const float*)d_in[2];
    const float* emaw = (const float*)d_in[3];
    float* out = (float*)d_out;

    // small scratch in ws (same footprint that always passed)
    int*   idx_ws  = (int*)d_ws;                       // NTOK ints
    float* x2v     = (float*)d_ws + NTOK;              // NTOK floats
    float* w2v     = x2v + NTOK;                       // KC floats
    float* lossacc = w2v + KC;                         // 1 float
    float* nsum    = lossacc + 1;                      // 1 float

    // big scratch inside not-yet-final d_out regions:
    float* zT   = out + OFF_Q;     // 16384x256 -> 256x16384 (16 MB)
    float* wT   = out + OFF_W;     //  8192x256 -> 256x8192  ( 8 MB)
    float* vbuf = out + OFF_EMA;                        // SPLIT*NTOK floats
    int*   kbuf = (int*)(out + OFF_EMA) + SPLIT * NTOK; // SPLIT*NTOK ints

    k_tr     <<<dim3(8, 512),     256, 0, stream>>>(z, zT, NTOK, DD);
    k_tr     <<<dim3(8, 256),     256, 0, stream>>>(w, wT, KC, DD);
    k_rownorm<<<NTOK / 16,        256, 0, stream>>>(z, x2v);
    k_rownorm<<<KC / 16,          256, 0, stream>>>(w, w2v);
    k_argmin <<<SPLIT * (NTOK / 128), 256, 0, stream>>>(zT, wT, x2v, w2v, vbuf, kbuf);
    k_reduce <<<NTOK / 256,       256, 0, stream>>>(vbuf, kbuf, idx_ws, out);
    k_init   <<<(KC * DD) / 256,  256, 0, stream>>>(emaw, ecs, out, lossacc);
    k_scatter<<<NTOK,             256, 0, stream>>>(z, w, idx_ws, out, lossacc);
    k_nsum   <<<1,                256, 0, stream>>>(out, lossacc, nsum);
    k_neww   <<<KC,               256, 0, stream>>>(out, nsum);
}